// Round 2
// baseline (23026.944 us; speedup 1.0000x reference)
//
#include <hip/hip_runtime.h>
#include <hip/hip_bf16.h>
#include <math.h>
#include <stdio.h>

#define N_NODES 20000
#define FDIM 20
#define DDIM 256
#define HH 8
#define LL 3
#define SS 4
#define EE 320000

// ---- GEMM: C = act(A@B + bias) or C += A@B, 64x64 tile, BK=16 ----
template<int ACT, bool ACCUM>
__global__ __launch_bounds__(256) void gemm_kernel(
    const float* __restrict__ A, const float* __restrict__ B,
    const float* __restrict__ bias, float* __restrict__ C,
    int M, int Nc, int K)
{
  __shared__ float As[16][65];
  __shared__ float Bs[16][65];
  const int tid = threadIdx.x;
  const int tx = tid & 15, ty = tid >> 4;
  const int row0 = blockIdx.y * 64, col0 = blockIdx.x * 64;
  const int am = tid >> 2, ak = (tid & 3) * 4;
  const int bk = tid >> 4, bc = (tid & 15) * 4;
  float acc[4][4] = {};
  for (int k0 = 0; k0 < K; k0 += 16) {
    float4 av = make_float4(0.f, 0.f, 0.f, 0.f);
    int garow = row0 + am;
    if (garow < M) {
      if (k0 + ak + 3 < K) {
        av = *(const float4*)(A + (size_t)garow * K + k0 + ak);
      } else {
        float t[4];
        #pragma unroll
        for (int j = 0; j < 4; j++)
          t[j] = (k0 + ak + j < K) ? A[(size_t)garow * K + k0 + ak + j] : 0.f;
        av = make_float4(t[0], t[1], t[2], t[3]);
      }
    }
    As[ak + 0][am] = av.x; As[ak + 1][am] = av.y;
    As[ak + 2][am] = av.z; As[ak + 3][am] = av.w;
    float4 bv = make_float4(0.f, 0.f, 0.f, 0.f);
    if (k0 + bk < K)
      bv = *(const float4*)(B + (size_t)(k0 + bk) * Nc + col0 + bc);
    Bs[bk][bc + 0] = bv.x; Bs[bk][bc + 1] = bv.y;
    Bs[bk][bc + 2] = bv.z; Bs[bk][bc + 3] = bv.w;
    __syncthreads();
    #pragma unroll
    for (int kk = 0; kk < 16; kk++) {
      float a[4], b[4];
      #pragma unroll
      for (int i = 0; i < 4; i++) a[i] = As[kk][ty * 4 + i];
      #pragma unroll
      for (int j = 0; j < 4; j++) b[j] = Bs[kk][tx * 4 + j];
      #pragma unroll
      for (int i = 0; i < 4; i++)
        #pragma unroll
        for (int j = 0; j < 4; j++)
          acc[i][j] = fmaf(a[i], b[j], acc[i][j]);
    }
    __syncthreads();
  }
  #pragma unroll
  for (int i = 0; i < 4; i++) {
    int row = row0 + ty * 4 + i;
    if (row >= M) continue;
    int col = col0 + tx * 4;
    float4 v;
    float* vp = &v.x;
    float4 prev = make_float4(0.f, 0.f, 0.f, 0.f);
    if (ACCUM) prev = *(const float4*)(C + (size_t)row * Nc + col);
    const float* pv = &prev.x;
    #pragma unroll
    for (int j = 0; j < 4; j++) {
      float t = acc[i][j] + (bias ? bias[col + j] : 0.f) + (ACCUM ? pv[j] : 0.f);
      if (ACT == 1) t = 0.5f * t * (1.f + erff(t * 0.7071067811865475f));
      vp[j] = t;
    }
    *(float4*)(C + (size_t)row * Nc + col) = v;
  }
}

// ---- elementwise helpers ----
__global__ void fill_kernel(float* __restrict__ p, float v, int n) {
  int i = blockIdx.x * blockDim.x + threadIdx.x;
  if (i < n) p[i] = v;
}

__global__ void add_emb_kernel(const float* __restrict__ se,
                               float* __restrict__ h) {
  int i = blockIdx.x * blockDim.x + threadIdx.x;
  if (i >= N_NODES * DDIM) return;
  h[i] = h[i] + se[i & (DDIM - 1)];
}

// ---- edge attention scores: one wave per edge ----
__global__ __launch_bounds__(256) void edge_attn_kernel(
    const float* __restrict__ Q, const float* __restrict__ K,
    const int* __restrict__ src, const int* __restrict__ dst,
    const int* __restrict__ scm, const float* __restrict__ fcw,
    const float* __restrict__ lam, int l,
    float* __restrict__ attn)
{
  int w = (blockIdx.x * blockDim.x + threadIdx.x) >> 6;
  int lane = threadIdx.x & 63;
  if (w >= EE) return;
  int s = src[w], d = dst[w];
  float4 q = ((const float4*)(Q + (size_t)d * DDIM))[lane];
  float4 k = ((const float4*)(K + (size_t)s * DDIM))[lane];
  float p = q.x * k.x + q.y * k.y + q.z * k.z + q.w * k.w;
  p += __shfl_xor(p, 1);
  p += __shfl_xor(p, 2);
  p += __shfl_xor(p, 4);
  if ((lane & 7) == 0) {
    float scv = (float)scm[w];
    attn[(size_t)w * HH + (lane >> 3)] =
        p * 0.17677669529663687f * scv + lam[l] * fcw[w];
  }
}

// ---- segment max (atomic) ----
__device__ inline void atomicMaxF(float* addr, float val) {
  if (val >= 0.f) atomicMax((int*)addr, __float_as_int(val));
  else            atomicMin((unsigned int*)addr, __float_as_uint(val));
}

__global__ void seg_max_kernel(const float* __restrict__ attn,
                               const int* __restrict__ dst,
                               float* __restrict__ m) {
  int i = blockIdx.x * blockDim.x + threadIdx.x;
  if (i >= EE * HH) return;
  int e = i >> 3, h = i & 7;
  atomicMaxF(&m[(size_t)dst[e] * HH + h], attn[i]);
}

// ---- exp + segment sum ----
__global__ void seg_exp_sum_kernel(float* __restrict__ attn,
                                   const int* __restrict__ dst,
                                   const float* __restrict__ m,
                                   float* __restrict__ ssum) {
  int i = blockIdx.x * blockDim.x + threadIdx.x;
  if (i >= EE * HH) return;
  int e = i >> 3, h = i & 7;
  int d = dst[e];
  float v = expf(attn[i] - m[(size_t)d * HH + h]);
  attn[i] = v;
  atomicAdd(&ssum[(size_t)d * HH + h], v);
}

// ---- scatter a*V[src] into agg[dst]: one wave per edge ----
__global__ __launch_bounds__(256) void scatter_kernel(
    const float* __restrict__ attn, const float* __restrict__ ssum,
    const float* __restrict__ V, const int* __restrict__ src,
    const int* __restrict__ dst, float* __restrict__ agg)
{
  int w = (blockIdx.x * blockDim.x + threadIdx.x) >> 6;
  int lane = threadIdx.x & 63;
  if (w >= EE) return;
  int s = src[w], d = dst[w];
  int h = lane >> 3;
  float a = attn[(size_t)w * HH + h] / (ssum[(size_t)d * HH + h] + 1e-16f);
  float4 v = ((const float4*)(V + (size_t)s * DDIM))[lane];
  float* base = agg + (size_t)d * DDIM + lane * 4;
  atomicAdd(base + 0, a * v.x);
  atomicAdd(base + 1, a * v.y);
  atomicAdd(base + 2, a * v.z);
  atomicAdd(base + 3, a * v.w);
}

// ---- LayerNorm(X [+ Y]) * g + b : one wave per row (X may alias out) ----
__global__ __launch_bounds__(256) void ln_kernel(
    const float* __restrict__ X, const float* __restrict__ Y,
    const float* __restrict__ g, const float* __restrict__ b,
    float* __restrict__ out, int M)
{
  int row = blockIdx.x * (blockDim.x >> 6) + (threadIdx.x >> 6);
  int lane = threadIdx.x & 63;
  if (row >= M) return;
  float4 x = ((const float4*)(X + (size_t)row * DDIM))[lane];
  if (Y) {
    float4 y = ((const float4*)(Y + (size_t)row * DDIM))[lane];
    x.x += y.x; x.y += y.y; x.z += y.z; x.w += y.w;
  }
  float s = x.x + x.y + x.z + x.w;
  #pragma unroll
  for (int mk = 1; mk < 64; mk <<= 1) s += __shfl_xor(s, mk);
  float mu = s * (1.f / DDIM);
  float d0 = x.x - mu, d1 = x.y - mu, d2 = x.z - mu, d3 = x.w - mu;
  float vs = d0 * d0 + d1 * d1 + d2 * d2 + d3 * d3;
  #pragma unroll
  for (int mk = 1; mk < 64; mk <<= 1) vs += __shfl_xor(vs, mk);
  float inv = rsqrtf(vs * (1.f / DDIM) + 1e-5f);
  float4 gg = ((const float4*)g)[lane];
  float4 bb = ((const float4*)b)[lane];
  float4 o;
  o.x = d0 * inv * gg.x + bb.x;
  o.y = d1 * inv * gg.y + bb.y;
  o.z = d2 * inv * gg.z + bb.z;
  o.w = d3 * inv * gg.w + bb.w;
  ((float4*)(out + (size_t)row * DDIM))[lane] = o;
}

// ---- host launch ----
extern "C" void kernel_launch(void* const* d_in, const int* in_sizes, int n_in,
                              void* d_out, int out_size, void* d_ws, size_t ws_size,
                              hipStream_t stream) {
  const float* x      = (const float*)d_in[0];
  const int*   ei     = (const int*)d_in[1];
  const int*   scm    = (const int*)d_in[2];
  const float* fcw    = (const float*)d_in[3];
  const float* in_w   = (const float*)d_in[4];
  const float* in_b   = (const float*)d_in[5];
  const float* st_emb = (const float*)d_in[6];
  const float* Wq     = (const float*)d_in[7];
  const float* Wk     = (const float*)d_in[8];
  const float* Wv     = (const float*)d_in[9];
  const float* Wo     = (const float*)d_in[10];
  const float* bo     = (const float*)d_in[11];
  const float* ln1g   = (const float*)d_in[12];
  const float* ln1b   = (const float*)d_in[13];
  const float* ln2g   = (const float*)d_in[14];
  const float* ln2b   = (const float*)d_in[15];
  const float* fw1    = (const float*)d_in[16];
  const float* fb1    = (const float*)d_in[17];
  const float* fw2    = (const float*)d_in[18];
  const float* fb2    = (const float*)d_in[19];
  const float* lam    = (const float*)d_in[20];
  const float* fus_w  = (const float*)d_in[21];
  const float* fus_b  = (const float*)d_in[22];
  const float* outg   = (const float*)d_in[23];
  const float* outb   = (const float*)d_in[24];

  const size_t ND = (size_t)N_NODES * DDIM;           // 5.12M floats
  float* W = (float*)d_ws;
  size_t off = 0;
  auto alloc = [&](size_t n) { float* p = W + off; off += n; return p; };
  float* f1   = alloc(ND * 4);   // FFN intermediate; aliases Qb/Kb/Vb/agg
  float* Qb   = f1;
  float* Kb   = f1 + ND;
  float* Vb   = f1 + 2 * ND;
  float* agg  = f1 + 3 * ND;
  float* h    = alloc(ND);
  float* out1 = alloc(ND);
  float* f2   = alloc(ND);
  float* attn = alloc((size_t)EE * HH);
  float* mbuf = alloc((size_t)N_NODES * HH);
  float* sbuf = alloc((size_t)N_NODES * HH);
  float* fus  = (float*)d_out;   // fusion accumulator lives in d_out

  static int printed = 0;
  if (!printed) {
    printed = 1;
    fprintf(stderr, "[kernel_launch] ws_size=%zu bytes, need=%zu bytes\n",
            ws_size, off * sizeof(float));
  }

  const int gM = (N_NODES + 63) / 64;
  dim3 gD(DDIM / 64, gM);
  dim3 gD4(4 * DDIM / 64, gM);
  const int edgeBlocks = (EE + 3) / 4;
  const int ehThreads  = (EE * HH + 255) / 256;
  const int ndBlocks   = (int)((ND + 255) / 256);
  const int lnBlocks   = (N_NODES + 3) / 4;
  const int nhBlocks   = (N_NODES * HH + 255) / 256;

  for (int s = 0; s < SS; s++) {
    const int* srcp = ei + (size_t)s * 2 * EE;
    const int* dstp = srcp + EE;
    const int* scs  = scm + (size_t)s * EE;
    const float* fcs = fcw + (size_t)s * EE;

    // h = x @ in_w + in_b ; then h += stage_emb[s]
    gemm_kernel<0, false><<<gD, 256, 0, stream>>>(x, in_w, in_b, h, N_NODES, DDIM, FDIM);
    add_emb_kernel<<<ndBlocks, 256, 0, stream>>>(st_emb + s * DDIM, h);

    for (int l = 0; l < LL; l++) {
      const size_t wo = (size_t)l * DDIM * DDIM;
      gemm_kernel<0, false><<<gD, 256, 0, stream>>>(h, Wq + wo, nullptr, Qb, N_NODES, DDIM, DDIM);
      gemm_kernel<0, false><<<gD, 256, 0, stream>>>(h, Wk + wo, nullptr, Kb, N_NODES, DDIM, DDIM);
      gemm_kernel<0, false><<<gD, 256, 0, stream>>>(h, Wv + wo, nullptr, Vb, N_NODES, DDIM, DDIM);

      fill_kernel<<<nhBlocks, 256, 0, stream>>>(mbuf, -INFINITY, N_NODES * HH);
      fill_kernel<<<nhBlocks, 256, 0, stream>>>(sbuf, 0.f, N_NODES * HH);
      fill_kernel<<<ndBlocks, 256, 0, stream>>>(agg, 0.f, (int)ND);

      edge_attn_kernel<<<edgeBlocks, 256, 0, stream>>>(Qb, Kb, srcp, dstp, scs, fcs, lam, l, attn);
      seg_max_kernel<<<ehThreads, 256, 0, stream>>>(attn, dstp, mbuf);
      seg_exp_sum_kernel<<<ehThreads, 256, 0, stream>>>(attn, dstp, mbuf, sbuf);
      scatter_kernel<<<edgeBlocks, 256, 0, stream>>>(attn, sbuf, Vb, srcp, dstp, agg);

      gemm_kernel<0, false><<<gD, 256, 0, stream>>>(agg, Wo + wo, bo + l * DDIM, f2, N_NODES, DDIM, DDIM);
      ln_kernel<<<lnBlocks, 256, 0, stream>>>(f2, h, ln1g + l * DDIM, ln1b + l * DDIM, out1, N_NODES);
      gemm_kernel<1, false><<<gD4, 256, 0, stream>>>(out1, fw1 + (size_t)l * DDIM * 4 * DDIM,
                                                     fb1 + l * 4 * DDIM, f1, N_NODES, 4 * DDIM, DDIM);
      gemm_kernel<0, false><<<gD, 256, 0, stream>>>(f1, fw2 + (size_t)l * 4 * DDIM * DDIM,
                                                    fb2 + l * DDIM, f2, N_NODES, DDIM, 4 * DDIM);
      ln_kernel<<<lnBlocks, 256, 0, stream>>>(f2, out1, ln2g + l * DDIM, ln2b + l * DDIM, h, N_NODES);
    }

    // fusion accumulate: fus (=d_out) (+)= h @ fus_w[s*D:(s+1)*D, :]  (+ fus_b on s==0)
    if (s == 0)
      gemm_kernel<0, false><<<gD, 256, 0, stream>>>(h, fus_w + (size_t)s * DDIM * DDIM,
                                                    fus_b, fus, N_NODES, DDIM, DDIM);
    else
      gemm_kernel<0, true><<<gD, 256, 0, stream>>>(h, fus_w + (size_t)s * DDIM * DDIM,
                                                   nullptr, fus, N_NODES, DDIM, DDIM);
  }

  // final LN in-place on d_out
  ln_kernel<<<lnBlocks, 256, 0, stream>>>(fus, nullptr, outg, outb, (float*)d_out, N_NODES);
}

// Round 3
// 4798.270 us; speedup vs baseline: 4.7990x; 4.7990x over previous
//
#include <hip/hip_runtime.h>
#include <hip/hip_bf16.h>
#include <math.h>

#define N_NODES 20000
#define FDIM 20
#define DDIM 256
#define HH 8
#define LL 3
#define SS 4
#define EE 320000

typedef __attribute__((ext_vector_type(8))) short bf16x8;
typedef __attribute__((ext_vector_type(4))) float f32x4;

__device__ inline unsigned short f2bf(float f) {
  unsigned u = __float_as_uint(f);
  unsigned r = u + 0x7FFFu + ((u >> 16) & 1u);
  return (unsigned short)(r >> 16);
}

// ---- f32 GEMM (only for x@in_w, K=20): C = A@B + bias ----
template<int ACT, bool ACCUM>
__global__ __launch_bounds__(256) void gemm_kernel(
    const float* __restrict__ A, const float* __restrict__ B,
    const float* __restrict__ bias, float* __restrict__ C,
    int M, int Nc, int K)
{
  __shared__ float As[16][65];
  __shared__ float Bs[16][65];
  const int tid = threadIdx.x;
  const int tx = tid & 15, ty = tid >> 4;
  const int row0 = blockIdx.y * 64, col0 = blockIdx.x * 64;
  const int am = tid >> 2, ak = (tid & 3) * 4;
  const int bk = tid >> 4, bc = (tid & 15) * 4;
  float acc[4][4] = {};
  for (int k0 = 0; k0 < K; k0 += 16) {
    float4 av = make_float4(0.f, 0.f, 0.f, 0.f);
    int garow = row0 + am;
    if (garow < M) {
      if (k0 + ak + 3 < K) {
        av = *(const float4*)(A + (size_t)garow * K + k0 + ak);
      } else {
        float t[4];
        #pragma unroll
        for (int j = 0; j < 4; j++)
          t[j] = (k0 + ak + j < K) ? A[(size_t)garow * K + k0 + ak + j] : 0.f;
        av = make_float4(t[0], t[1], t[2], t[3]);
      }
    }
    As[ak + 0][am] = av.x; As[ak + 1][am] = av.y;
    As[ak + 2][am] = av.z; As[ak + 3][am] = av.w;
    float4 bv = make_float4(0.f, 0.f, 0.f, 0.f);
    if (k0 + bk < K)
      bv = *(const float4*)(B + (size_t)(k0 + bk) * Nc + col0 + bc);
    Bs[bk][bc + 0] = bv.x; Bs[bk][bc + 1] = bv.y;
    Bs[bk][bc + 2] = bv.z; Bs[bk][bc + 3] = bv.w;
    __syncthreads();
    #pragma unroll
    for (int kk = 0; kk < 16; kk++) {
      float a[4], b[4];
      #pragma unroll
      for (int i = 0; i < 4; i++) a[i] = As[kk][ty * 4 + i];
      #pragma unroll
      for (int j = 0; j < 4; j++) b[j] = Bs[kk][tx * 4 + j];
      #pragma unroll
      for (int i = 0; i < 4; i++)
        #pragma unroll
        for (int j = 0; j < 4; j++)
          acc[i][j] = fmaf(a[i], b[j], acc[i][j]);
    }
    __syncthreads();
  }
  #pragma unroll
  for (int i = 0; i < 4; i++) {
    int row = row0 + ty * 4 + i;
    if (row >= M) continue;
    int col = col0 + tx * 4;
    float4 v;
    float* vp = &v.x;
    #pragma unroll
    for (int j = 0; j < 4; j++) vp[j] = acc[i][j] + (bias ? bias[col + j] : 0.f);
    *(float4*)(C + (size_t)row * Nc + col) = v;
  }
}

// ---- bf16 MFMA GEMM: C = act(A@B + bias [+C]), A f32 [M,K], BT bf16 [Nc, ldb] ----
// 128x128 tile, BK=32, 4 waves each computing 64x64 via 4x4 frags of 16x16x32.
template<int ACT, bool ACCUM>
__global__ __launch_bounds__(256) void mfma_gemm_kernel(
    const float* __restrict__ A, const unsigned short* __restrict__ BT,
    const float* __restrict__ bias, float* __restrict__ C,
    int M, int Nc, int K, int ldb, int bk0)
{
  __shared__ unsigned short As[128][40];   // pad 32->40 to spread banks
  __shared__ unsigned short Bs[128][40];
  const int tid = threadIdx.x;
  const int lane = tid & 63;
  const int wid = tid >> 6;
  const int wr = (wid >> 1) * 64, wc = (wid & 1) * 64;
  const int row0 = blockIdx.y * 128, col0 = blockIdx.x * 128;
  f32x4 acc[4][4] = {};
  for (int k0 = 0; k0 < K; k0 += 32) {
    #pragma unroll
    for (int p = 0; p < 4; p++) {                  // stage A (f32 -> bf16)
      int r = p * 32 + (tid >> 3);
      int kk = (tid & 7) * 4;
      float4 av = make_float4(0.f, 0.f, 0.f, 0.f);
      int gr = row0 + r;
      if (gr < M) av = *(const float4*)(A + (size_t)gr * K + k0 + kk);
      ushort4 bv;
      bv.x = f2bf(av.x); bv.y = f2bf(av.y); bv.z = f2bf(av.z); bv.w = f2bf(av.w);
      *(ushort4*)&As[r][kk] = bv;
    }
    #pragma unroll
    for (int p = 0; p < 4; p++) {                  // stage B (already bf16)
      int n = p * 32 + (tid >> 3);
      int kk = (tid & 7) * 4;
      ushort4 bv = *(const ushort4*)(BT + (size_t)(col0 + n) * ldb + bk0 + k0 + kk);
      *(ushort4*)&Bs[n][kk] = bv;
    }
    __syncthreads();
    bf16x8 af[4], bfv[4];
    #pragma unroll
    for (int mi = 0; mi < 4; mi++)
      af[mi] = *(const bf16x8*)&As[wr + mi * 16 + (lane & 15)][(lane >> 4) * 8];
    #pragma unroll
    for (int ni = 0; ni < 4; ni++)
      bfv[ni] = *(const bf16x8*)&Bs[wc + ni * 16 + (lane & 15)][(lane >> 4) * 8];
    #pragma unroll
    for (int mi = 0; mi < 4; mi++)
      #pragma unroll
      for (int ni = 0; ni < 4; ni++)
        acc[mi][ni] = __builtin_amdgcn_mfma_f32_16x16x32_bf16(af[mi], bfv[ni], acc[mi][ni], 0, 0, 0);
    __syncthreads();
  }
  #pragma unroll
  for (int mi = 0; mi < 4; mi++) {
    #pragma unroll
    for (int ni = 0; ni < 4; ni++) {
      int col = col0 + wc + ni * 16 + (lane & 15);
      float bval = bias ? bias[col] : 0.f;
      #pragma unroll
      for (int j = 0; j < 4; j++) {
        int row = row0 + wr + mi * 16 + (lane >> 4) * 4 + j;
        if (row < M) {
          float t = acc[mi][ni][j] + bval;
          if (ACCUM) t += C[(size_t)row * Nc + col];
          if (ACT == 1) t = 0.5f * t * (1.f + erff(t * 0.7071067811865475f));
          C[(size_t)row * Nc + col] = t;
        }
      }
    }
  }
}

// ---- weight transpose + bf16 cast: WT[n*K+k] = bf16(W[k*Nn+n]) ----
__global__ void transpose_bf16_kernel(const float* __restrict__ W,
                                      unsigned short* __restrict__ WT,
                                      int K, int Nn) {
  int i = blockIdx.x * blockDim.x + threadIdx.x;
  if (i >= K * Nn) return;
  int n = i / K, k = i - n * K;
  WT[i] = f2bf(W[(size_t)k * Nn + n]);
}

// ---- small helpers ----
__global__ void fill_kernel(float* __restrict__ p, float v, int n) {
  int i = blockIdx.x * blockDim.x + threadIdx.x;
  if (i < n) p[i] = v;
}

__global__ void bias2_kernel(const float* __restrict__ a,
                             const float* __restrict__ b,
                             float* __restrict__ o) {
  int i = threadIdx.x;
  o[i] = a[i] + b[i];
}

// ---- CSR build ----
__global__ void hist_kernel(const int* __restrict__ dst, int* __restrict__ deg) {
  int e = blockIdx.x * blockDim.x + threadIdx.x;
  if (e < EE) atomicAdd(&deg[dst[e]], 1);
}

__global__ __launch_bounds__(1024) void scan_kernel(const int* __restrict__ deg,
                                                    int* __restrict__ rowptr) {
  __shared__ int part[1024];
  const int t = threadIdx.x;
  const int CH = (N_NODES + 1023) / 1024;
  int base = t * CH, s = 0;
  for (int i = 0; i < CH; i++) {
    int idx = base + i;
    if (idx < N_NODES) s += deg[idx];
  }
  part[t] = s;
  __syncthreads();
  for (int off = 1; off < 1024; off <<= 1) {
    int v = (t >= off) ? part[t - off] : 0;
    __syncthreads();
    part[t] += v;
    __syncthreads();
  }
  int run = (t == 0) ? 0 : part[t - 1];
  for (int i = 0; i < CH; i++) {
    int idx = base + i;
    if (idx < N_NODES) { rowptr[idx] = run; run += deg[idx]; }
  }
  if (t == 1023) rowptr[N_NODES] = run;
}

__global__ void csrfill_kernel(const int* __restrict__ src, const int* __restrict__ dst,
                               const int* __restrict__ scm, const float* __restrict__ fcw,
                               const int* __restrict__ rowptr, int* __restrict__ cur,
                               int* __restrict__ epack, float* __restrict__ efw) {
  int e = blockIdx.x * blockDim.x + threadIdx.x;
  if (e >= EE) return;
  int d = dst[e];
  int slot = rowptr[d] + atomicAdd(&cur[d], 1);
  epack[slot] = src[e] | (scm[e] << 31);
  efw[slot] = fcw[e];
}

// ---- fused edge attention + aggregation: one wave per dst node ----
__global__ __launch_bounds__(256) void attn_agg_kernel(
    const float* __restrict__ Q, const float* __restrict__ Kt,
    const float* __restrict__ V, const int* __restrict__ rowptr,
    const int* __restrict__ epack, const float* __restrict__ efw,
    const float* __restrict__ lam, int l, float* __restrict__ agg)
{
  int node = blockIdx.x * 4 + (threadIdx.x >> 6);
  int lane = threadIdx.x & 63;
  if (node >= N_NODES) return;
  const float laml = lam[l];
  float4 q = ((const float4*)(Q + (size_t)node * DDIM))[lane];
  int beg = rowptr[node], end = rowptr[node + 1];
  float m = -INFINITY, ss = 0.f;
  float ax = 0.f, ay = 0.f, az = 0.f, aw = 0.f;
  for (int i = beg; i < end; i++) {
    int pk = epack[i];
    int s = pk & 0x7FFFFFFF;
    float sc = (float)(((unsigned)pk) >> 31);
    float fw = efw[i];
    float4 kv = ((const float4*)(Kt + (size_t)s * DDIM))[lane];
    float dot = q.x * kv.x + q.y * kv.y + q.z * kv.z + q.w * kv.w;
    dot += __shfl_xor(dot, 1);
    dot += __shfl_xor(dot, 2);
    dot += __shfl_xor(dot, 4);
    float score = dot * 0.17677669529663687f * sc + laml * fw;
    float mn = fmaxf(m, score);
    float corr = __expf(m - mn);     // m=-inf first iter -> 0
    float p = __expf(score - mn);
    ss = ss * corr + p;
    float4 vv = ((const float4*)(V + (size_t)s * DDIM))[lane];
    ax = ax * corr + p * vv.x;
    ay = ay * corr + p * vv.y;
    az = az * corr + p * vv.z;
    aw = aw * corr + p * vv.w;
    m = mn;
  }
  float inv = 1.f / (ss + 1e-16f);
  float4 o = make_float4(ax * inv, ay * inv, az * inv, aw * inv);
  ((float4*)(agg + (size_t)node * DDIM))[lane] = o;
}

// ---- LayerNorm(X [+ Y]) * g + b : one wave per row (X may alias out) ----
__global__ __launch_bounds__(256) void ln_kernel(
    const float* __restrict__ X, const float* __restrict__ Y,
    const float* __restrict__ g, const float* __restrict__ b,
    float* __restrict__ out, int M)
{
  int row = blockIdx.x * (blockDim.x >> 6) + (threadIdx.x >> 6);
  int lane = threadIdx.x & 63;
  if (row >= M) return;
  float4 x = ((const float4*)(X + (size_t)row * DDIM))[lane];
  if (Y) {
    float4 y = ((const float4*)(Y + (size_t)row * DDIM))[lane];
    x.x += y.x; x.y += y.y; x.z += y.z; x.w += y.w;
  }
  float s = x.x + x.y + x.z + x.w;
  #pragma unroll
  for (int mk = 1; mk < 64; mk <<= 1) s += __shfl_xor(s, mk);
  float mu = s * (1.f / DDIM);
  float d0 = x.x - mu, d1 = x.y - mu, d2 = x.z - mu, d3 = x.w - mu;
  float vs = d0 * d0 + d1 * d1 + d2 * d2 + d3 * d3;
  #pragma unroll
  for (int mk = 1; mk < 64; mk <<= 1) vs += __shfl_xor(vs, mk);
  float inv = rsqrtf(vs * (1.f / DDIM) + 1e-5f);
  float4 gg = ((const float4*)g)[lane];
  float4 bb = ((const float4*)b)[lane];
  float4 o;
  o.x = d0 * inv * gg.x + bb.x;
  o.y = d1 * inv * gg.y + bb.y;
  o.z = d2 * inv * gg.z + bb.z;
  o.w = d3 * inv * gg.w + bb.w;
  ((float4*)(out + (size_t)row * DDIM))[lane] = o;
}

// ---- host launch ----
extern "C" void kernel_launch(void* const* d_in, const int* in_sizes, int n_in,
                              void* d_out, int out_size, void* d_ws, size_t ws_size,
                              hipStream_t stream) {
  const float* x      = (const float*)d_in[0];
  const int*   ei     = (const int*)d_in[1];
  const int*   scm    = (const int*)d_in[2];
  const float* fcw    = (const float*)d_in[3];
  const float* in_w   = (const float*)d_in[4];
  const float* in_b   = (const float*)d_in[5];
  const float* st_emb = (const float*)d_in[6];
  const float* Wq     = (const float*)d_in[7];
  const float* Wk     = (const float*)d_in[8];
  const float* Wv     = (const float*)d_in[9];
  const float* Wo     = (const float*)d_in[10];
  const float* bo     = (const float*)d_in[11];
  const float* ln1g   = (const float*)d_in[12];
  const float* ln1b   = (const float*)d_in[13];
  const float* ln2g   = (const float*)d_in[14];
  const float* ln2b   = (const float*)d_in[15];
  const float* fw1    = (const float*)d_in[16];
  const float* fb1    = (const float*)d_in[17];
  const float* fw2    = (const float*)d_in[18];
  const float* fb2    = (const float*)d_in[19];
  const float* lam    = (const float*)d_in[20];
  const float* fus_w  = (const float*)d_in[21];
  const float* fus_b  = (const float*)d_in[22];
  const float* outg   = (const float*)d_in[23];
  const float* outb   = (const float*)d_in[24];

  const size_t ND = (size_t)N_NODES * DDIM;
  const int DD = DDIM * DDIM;                  // 65536
  float* W = (float*)d_ws;
  size_t off = 0;
  auto alloc = [&](size_t n) { float* p = W + off; off += n; return p; };
  float* f1   = alloc(ND * 4);    // aliases Qb/Kb/Vb/agg
  float* Qb   = f1;
  float* Kb   = f1 + ND;
  float* Vb   = f1 + 2 * ND;
  float* agg  = f1 + 3 * ND;
  float* h    = alloc(ND);
  float* out1 = alloc(ND);
  float* f2   = alloc(ND);
  unsigned short* bfb = (unsigned short*)alloc(1310720);  // 2,621,440 bf16
  unsigned short* wqT  = bfb;
  unsigned short* wkT  = bfb + 196608;
  unsigned short* wvT  = bfb + 393216;
  unsigned short* woT  = bfb + 589824;
  unsigned short* fw1T = bfb + 786432;
  unsigned short* fw2T = bfb + 1572864;
  unsigned short* fusT = bfb + 2359296;
  int*   rowptr = (int*)alloc(N_NODES + 1);
  int*   deg    = (int*)alloc(N_NODES);
  int*   cur    = (int*)alloc(N_NODES);
  int*   epack  = (int*)alloc(EE);
  float* efw    = alloc(EE);
  float* bias2  = alloc(DDIM);
  float* fus    = (float*)d_out;

  // ---- transpose weights to bf16 B^T once ----
  for (int l = 0; l < LL; l++) {
    transpose_bf16_kernel<<<(DD + 255) / 256, 256, 0, stream>>>(Wq + (size_t)l * DD, wqT + (size_t)l * DD, DDIM, DDIM);
    transpose_bf16_kernel<<<(DD + 255) / 256, 256, 0, stream>>>(Wk + (size_t)l * DD, wkT + (size_t)l * DD, DDIM, DDIM);
    transpose_bf16_kernel<<<(DD + 255) / 256, 256, 0, stream>>>(Wv + (size_t)l * DD, wvT + (size_t)l * DD, DDIM, DDIM);
    transpose_bf16_kernel<<<(DD + 255) / 256, 256, 0, stream>>>(Wo + (size_t)l * DD, woT + (size_t)l * DD, DDIM, DDIM);
    transpose_bf16_kernel<<<(4 * DD + 255) / 256, 256, 0, stream>>>(fw1 + (size_t)l * 4 * DD, fw1T + (size_t)l * 4 * DD, DDIM, 4 * DDIM);
    transpose_bf16_kernel<<<(4 * DD + 255) / 256, 256, 0, stream>>>(fw2 + (size_t)l * 4 * DD, fw2T + (size_t)l * 4 * DD, 4 * DDIM, DDIM);
  }
  transpose_bf16_kernel<<<(4 * DD + 255) / 256, 256, 0, stream>>>(fus_w, fusT, 4 * DDIM, DDIM);

  const int gMn = (N_NODES + 127) / 128;       // 157
  dim3 g256(2, gMn), g1024(8, gMn);
  dim3 gF32(DDIM / 64, (N_NODES + 63) / 64);
  const int lnBlocks = (N_NODES + 3) / 4;
  const int aggBlocks = (N_NODES + 3) / 4;
  const int eBlocks = (EE + 255) / 256;
  const int nBlocks = (N_NODES + 255) / 256;

  for (int s = 0; s < SS; s++) {
    const int* srcp = ei + (size_t)s * 2 * EE;
    const int* dstp = srcp + EE;
    const int* scs  = scm + (size_t)s * EE;
    const float* fcs = fcw + (size_t)s * EE;

    // CSR build for this stage
    fill_kernel<<<nBlocks, 256, 0, stream>>>((float*)deg, 0.f, N_NODES);
    fill_kernel<<<nBlocks, 256, 0, stream>>>((float*)cur, 0.f, N_NODES);
    hist_kernel<<<eBlocks, 256, 0, stream>>>(dstp, deg);
    scan_kernel<<<1, 1024, 0, stream>>>(deg, rowptr);
    csrfill_kernel<<<eBlocks, 256, 0, stream>>>(srcp, dstp, scs, fcs, rowptr, cur, epack, efw);

    // h = x @ in_w + (in_b + stage_emb[s])
    bias2_kernel<<<1, DDIM, 0, stream>>>(in_b, st_emb + s * DDIM, bias2);
    gemm_kernel<0, false><<<gF32, 256, 0, stream>>>(x, in_w, bias2, h, N_NODES, DDIM, FDIM);

    for (int l = 0; l < LL; l++) {
      const size_t wo = (size_t)l * DD;
      mfma_gemm_kernel<0, false><<<g256, 256, 0, stream>>>(h, wqT + wo, nullptr, Qb, N_NODES, DDIM, DDIM, DDIM, 0);
      mfma_gemm_kernel<0, false><<<g256, 256, 0, stream>>>(h, wkT + wo, nullptr, Kb, N_NODES, DDIM, DDIM, DDIM, 0);
      mfma_gemm_kernel<0, false><<<g256, 256, 0, stream>>>(h, wvT + wo, nullptr, Vb, N_NODES, DDIM, DDIM, DDIM, 0);

      attn_agg_kernel<<<aggBlocks, 256, 0, stream>>>(Qb, Kb, Vb, rowptr, epack, efw, lam, l, agg);

      mfma_gemm_kernel<0, false><<<g256, 256, 0, stream>>>(agg, woT + wo, bo + l * DDIM, f2, N_NODES, DDIM, DDIM, DDIM, 0);
      ln_kernel<<<lnBlocks, 256, 0, stream>>>(f2, h, ln1g + l * DDIM, ln1b + l * DDIM, out1, N_NODES);
      mfma_gemm_kernel<1, false><<<g1024, 256, 0, stream>>>(out1, fw1T + (size_t)l * 4 * DD,
                                                           fb1 + l * 4 * DDIM, f1, N_NODES, 4 * DDIM, DDIM, DDIM, 0);
      mfma_gemm_kernel<0, false><<<g256, 256, 0, stream>>>(f1, fw2T + (size_t)l * 4 * DD,
                                                           fb2 + l * DDIM, f2, N_NODES, DDIM, 4 * DDIM, 4 * DDIM, 0);
      ln_kernel<<<lnBlocks, 256, 0, stream>>>(f2, out1, ln2g + l * DDIM, ln2b + l * DDIM, h, N_NODES);
    }

    // fusion accumulate into d_out: fus (+)= h @ fus_w[s*D:(s+1)*D, :]
    if (s == 0)
      mfma_gemm_kernel<0, false><<<g256, 256, 0, stream>>>(h, fusT, fus_b, fus, N_NODES, DDIM, DDIM, 4 * DDIM, s * DDIM);
    else
      mfma_gemm_kernel<0, true><<<g256, 256, 0, stream>>>(h, fusT, nullptr, fus, N_NODES, DDIM, DDIM, 4 * DDIM, s * DDIM);
  }

  // final LN in-place on d_out
  ln_kernel<<<lnBlocks, 256, 0, stream>>>(fus, nullptr, outg, outb, (float*)d_out, N_NODES);
}

// Round 4
// 3163.327 us; speedup vs baseline: 7.2793x; 1.5168x over previous
//
#include <hip/hip_runtime.h>
#include <hip/hip_bf16.h>
#include <math.h>

#define N_NODES 20000
#define FDIM 20
#define DDIM 256
#define HH 8
#define LL 3
#define SS 4
#define EE 320000

typedef __attribute__((ext_vector_type(8))) short bf16x8;
typedef __attribute__((ext_vector_type(8))) unsigned short u16x8;
typedef __attribute__((ext_vector_type(4))) float f32x4;

__device__ inline unsigned short f2bf(float f) {
  unsigned u = __float_as_uint(f);
  unsigned r = u + 0x7FFFu + ((u >> 16) & 1u);
  return (unsigned short)(r >> 16);
}
__device__ inline float bf2f(unsigned short u) {
  return __uint_as_float(((unsigned)u) << 16);
}

// ---- f32 GEMM (x@in_w, K=20): C = A@B + bias, dual f32+bf16 out ----
__global__ __launch_bounds__(256) void gemm_f32_kernel(
    const float* __restrict__ A, const float* __restrict__ B,
    const float* __restrict__ bias, float* __restrict__ C,
    unsigned short* __restrict__ C2, int M, int Nc, int K)
{
  __shared__ float As[16][65];
  __shared__ float Bs[16][65];
  const int tid = threadIdx.x;
  const int tx = tid & 15, ty = tid >> 4;
  const int row0 = blockIdx.y * 64, col0 = blockIdx.x * 64;
  const int am = tid >> 2, ak = (tid & 3) * 4;
  const int bk = tid >> 4, bc = (tid & 15) * 4;
  float acc[4][4] = {};
  for (int k0 = 0; k0 < K; k0 += 16) {
    float4 av = make_float4(0.f, 0.f, 0.f, 0.f);
    int garow = row0 + am;
    if (garow < M) {
      if (k0 + ak + 3 < K) {
        av = *(const float4*)(A + (size_t)garow * K + k0 + ak);
      } else {
        float t[4];
        #pragma unroll
        for (int j = 0; j < 4; j++)
          t[j] = (k0 + ak + j < K) ? A[(size_t)garow * K + k0 + ak + j] : 0.f;
        av = make_float4(t[0], t[1], t[2], t[3]);
      }
    }
    As[ak + 0][am] = av.x; As[ak + 1][am] = av.y;
    As[ak + 2][am] = av.z; As[ak + 3][am] = av.w;
    float4 bv = make_float4(0.f, 0.f, 0.f, 0.f);
    if (k0 + bk < K)
      bv = *(const float4*)(B + (size_t)(k0 + bk) * Nc + col0 + bc);
    Bs[bk][bc + 0] = bv.x; Bs[bk][bc + 1] = bv.y;
    Bs[bk][bc + 2] = bv.z; Bs[bk][bc + 3] = bv.w;
    __syncthreads();
    #pragma unroll
    for (int kk = 0; kk < 16; kk++) {
      float a[4], b[4];
      #pragma unroll
      for (int i = 0; i < 4; i++) a[i] = As[kk][ty * 4 + i];
      #pragma unroll
      for (int j = 0; j < 4; j++) b[j] = Bs[kk][tx * 4 + j];
      #pragma unroll
      for (int i = 0; i < 4; i++)
        #pragma unroll
        for (int j = 0; j < 4; j++)
          acc[i][j] = fmaf(a[i], b[j], acc[i][j]);
    }
    __syncthreads();
  }
  #pragma unroll
  for (int i = 0; i < 4; i++) {
    int row = row0 + ty * 4 + i;
    if (row >= M) continue;
    int col = col0 + tx * 4;
    float4 v;
    ushort4 vb;
    float* vp = &v.x;
    #pragma unroll
    for (int j = 0; j < 4; j++) vp[j] = acc[i][j] + bias[col + j];
    vb.x = f2bf(v.x); vb.y = f2bf(v.y); vb.z = f2bf(v.z); vb.w = f2bf(v.w);
    *(float4*)(C + (size_t)row * Nc + col) = v;
    *(ushort4*)(C2 + (size_t)row * Nc + col) = vb;
  }
}

// ---- bf16 MFMA GEMM: out = act(A@B + bias [+Cf]), A bf16 [M,K], BT bf16 [Nc,ldb] ----
// 128x128 tile, BK=32, 4 waves, 4x4 frags of 16x16x32. OUTBF: write Cb bf16 else Cf f32.
template<int ACT, int OUTBF, bool ACCUM>
__global__ __launch_bounds__(256) void mfma_gemm_bf(
    const unsigned short* __restrict__ A, const unsigned short* __restrict__ BT,
    const float* __restrict__ bias, float* __restrict__ Cf,
    unsigned short* __restrict__ Cb, int ldc,
    int M, int K, int ldb, int bk0)
{
  __shared__ unsigned short As[128][40];   // 80B row: 16B-aligned, 2-way banks max
  __shared__ unsigned short Bs[128][40];
  const int tid = threadIdx.x;
  const int lane = tid & 63;
  const int wid = tid >> 6;
  const int wr = (wid >> 1) * 64, wc = (wid & 1) * 64;
  const int row0 = blockIdx.y * 128, col0 = blockIdx.x * 128;
  const int sr = tid >> 2, sk = (tid & 3) * 8;
  f32x4 acc[4][4] = {};
  for (int k0 = 0; k0 < K; k0 += 32) {
    #pragma unroll
    for (int p = 0; p < 2; p++) {
      int r = p * 64 + sr;
      int gr = row0 + r;
      u16x8 av = {0,0,0,0,0,0,0,0};
      if (gr < M) av = *(const u16x8*)(A + (size_t)gr * K + k0 + sk);
      *(u16x8*)&As[r][sk] = av;
      int n = p * 64 + sr;
      u16x8 bv = *(const u16x8*)(BT + (size_t)(col0 + n) * ldb + bk0 + k0 + sk);
      *(u16x8*)&Bs[n][sk] = bv;
    }
    __syncthreads();
    bf16x8 af[4], bfv[4];
    #pragma unroll
    for (int mi = 0; mi < 4; mi++)
      af[mi] = *(const bf16x8*)&As[wr + mi * 16 + (lane & 15)][(lane >> 4) * 8];
    #pragma unroll
    for (int ni = 0; ni < 4; ni++)
      bfv[ni] = *(const bf16x8*)&Bs[wc + ni * 16 + (lane & 15)][(lane >> 4) * 8];
    #pragma unroll
    for (int mi = 0; mi < 4; mi++)
      #pragma unroll
      for (int ni = 0; ni < 4; ni++)
        acc[mi][ni] = __builtin_amdgcn_mfma_f32_16x16x32_bf16(af[mi], bfv[ni], acc[mi][ni], 0, 0, 0);
    __syncthreads();
  }
  #pragma unroll
  for (int mi = 0; mi < 4; mi++) {
    #pragma unroll
    for (int ni = 0; ni < 4; ni++) {
      int col = col0 + wc + ni * 16 + (lane & 15);
      float bval = bias ? bias[col] : 0.f;
      #pragma unroll
      for (int j = 0; j < 4; j++) {
        int row = row0 + wr + mi * 16 + (lane >> 4) * 4 + j;
        if (row < M) {
          float t = acc[mi][ni][j] + bval;
          if (ACCUM) t += Cf[(size_t)row * ldc + col];
          if (ACT == 1) t = 0.5f * t * (1.f + erff(t * 0.7071067811865475f));
          if (OUTBF) Cb[(size_t)row * ldc + col] = f2bf(t);
          else       Cf[(size_t)row * ldc + col] = t;
        }
      }
    }
  }
}

// ---- weight transpose + bf16 cast: WT[n*K+k] = bf16(W[k*Nn+n]) ----
__global__ void transpose_bf16_kernel(const float* __restrict__ W,
                                      unsigned short* __restrict__ WT,
                                      int K, int Nn) {
  int i = blockIdx.x * blockDim.x + threadIdx.x;
  if (i >= K * Nn) return;
  int n = i / K, k = i - n * K;
  WT[i] = f2bf(W[(size_t)k * Nn + n]);
}

// ---- small helpers ----
__global__ void ifill_kernel(int* __restrict__ p, int v, int n) {
  int i = blockIdx.x * blockDim.x + threadIdx.x;
  if (i < n) p[i] = v;
}
__global__ void bias2_kernel(const float* __restrict__ a,
                             const float* __restrict__ b,
                             float* __restrict__ o) {
  int i = threadIdx.x;
  o[i] = a[i] + b[i];
}

// ---- CSR build ----
__global__ void hist_kernel(const int* __restrict__ dst, int* __restrict__ deg) {
  int e = blockIdx.x * blockDim.x + threadIdx.x;
  if (e < EE) atomicAdd(&deg[dst[e]], 1);
}

__global__ __launch_bounds__(1024) void scan_kernel(const int* __restrict__ deg,
                                                    int* __restrict__ rowptr) {
  __shared__ int part[1024];
  const int t = threadIdx.x;
  const int CH = (N_NODES + 1023) / 1024;
  int base = t * CH, s = 0;
  for (int i = 0; i < CH; i++) {
    int idx = base + i;
    if (idx < N_NODES) s += deg[idx];
  }
  part[t] = s;
  __syncthreads();
  for (int off = 1; off < 1024; off <<= 1) {
    int v = (t >= off) ? part[t - off] : 0;
    __syncthreads();
    part[t] += v;
    __syncthreads();
  }
  int run = (t == 0) ? 0 : part[t - 1];
  for (int i = 0; i < CH; i++) {
    int idx = base + i;
    if (idx < N_NODES) { rowptr[idx] = run; run += deg[idx]; }
  }
  if (t == 1023) rowptr[N_NODES] = run;
}

__global__ void csrfill_kernel(const int* __restrict__ src, const int* __restrict__ dst,
                               const int* __restrict__ scm, const float* __restrict__ fcw,
                               const int* __restrict__ rowptr, int* __restrict__ cur,
                               int* __restrict__ epack, float* __restrict__ efw) {
  int e = blockIdx.x * blockDim.x + threadIdx.x;
  if (e >= EE) return;
  int d = dst[e];
  int slot = rowptr[d] + atomicAdd(&cur[d], 1);
  epack[slot] = src[e] | (scm[e] << 31);
  efw[slot] = fcw[e];
}

// ---- fused edge attention + aggregation over bf16 QKV (one wave per dst) ----
// QKV row layout per node: [Q 256 | K 256 | V 256] bf16, stride 768.
__global__ __launch_bounds__(256) void attn_agg_kernel(
    const unsigned short* __restrict__ QKV,
    const int* __restrict__ rowptr, const int* __restrict__ epack,
    const float* __restrict__ efw, const float* __restrict__ lam, int l,
    unsigned short* __restrict__ agg)
{
  int node = blockIdx.x * 4 + (threadIdx.x >> 6);
  int lane = threadIdx.x & 63;
  if (node >= N_NODES) return;
  const float laml = lam[l];
  ushort4 q4 = *(const ushort4*)(QKV + (size_t)node * 768 + lane * 4);
  float qx = bf2f(q4.x), qy = bf2f(q4.y), qz = bf2f(q4.z), qw = bf2f(q4.w);
  int beg = rowptr[node], end = rowptr[node + 1];
  float m = -INFINITY, ss = 0.f;
  float ax = 0.f, ay = 0.f, az = 0.f, aw = 0.f;
  for (int i = beg; i < end; i++) {
    int pk = epack[i];
    int s = pk & 0x7FFFFFFF;
    float sc = (float)(((unsigned)pk) >> 31);
    float fw = efw[i];
    const unsigned short* kp = QKV + (size_t)s * 768 + 256 + lane * 4;
    ushort4 k4 = *(const ushort4*)kp;          // K row
    ushort4 v4 = *(const ushort4*)(kp + 256);  // V row (adjacent 512B)
    float dot = qx * bf2f(k4.x) + qy * bf2f(k4.y) + qz * bf2f(k4.z) + qw * bf2f(k4.w);
    dot += __shfl_xor(dot, 1);
    dot += __shfl_xor(dot, 2);
    dot += __shfl_xor(dot, 4);
    float score = dot * 0.17677669529663687f * sc + laml * fw;
    float mn = fmaxf(m, score);
    float corr = __expf(m - mn);
    float p = __expf(score - mn);
    ss = ss * corr + p;
    ax = ax * corr + p * bf2f(v4.x);
    ay = ay * corr + p * bf2f(v4.y);
    az = az * corr + p * bf2f(v4.z);
    aw = aw * corr + p * bf2f(v4.w);
    m = mn;
  }
  float inv = 1.f / (ss + 1e-16f);
  ushort4 o;
  o.x = f2bf(ax * inv); o.y = f2bf(ay * inv);
  o.z = f2bf(az * inv); o.w = f2bf(aw * inv);
  *(ushort4*)(agg + (size_t)node * DDIM + lane * 4) = o;
}

// ---- LayerNorm(X [+ Y]) * g + b : one wave per row, dual f32+bf16 out ----
__global__ __launch_bounds__(256) void ln_kernel(
    const float* __restrict__ X, const float* __restrict__ Y,
    const float* __restrict__ g, const float* __restrict__ b,
    float* __restrict__ out, unsigned short* __restrict__ outb, int M)
{
  int row = blockIdx.x * (blockDim.x >> 6) + (threadIdx.x >> 6);
  int lane = threadIdx.x & 63;
  if (row >= M) return;
  float4 x = ((const float4*)(X + (size_t)row * DDIM))[lane];
  if (Y) {
    float4 y = ((const float4*)(Y + (size_t)row * DDIM))[lane];
    x.x += y.x; x.y += y.y; x.z += y.z; x.w += y.w;
  }
  float s = x.x + x.y + x.z + x.w;
  #pragma unroll
  for (int mk = 1; mk < 64; mk <<= 1) s += __shfl_xor(s, mk);
  float mu = s * (1.f / DDIM);
  float d0 = x.x - mu, d1 = x.y - mu, d2 = x.z - mu, d3 = x.w - mu;
  float vs = d0 * d0 + d1 * d1 + d2 * d2 + d3 * d3;
  #pragma unroll
  for (int mk = 1; mk < 64; mk <<= 1) vs += __shfl_xor(vs, mk);
  float inv = rsqrtf(vs * (1.f / DDIM) + 1e-5f);
  float4 gg = ((const float4*)g)[lane];
  float4 bb = ((const float4*)b)[lane];
  float4 o;
  o.x = d0 * inv * gg.x + bb.x;
  o.y = d1 * inv * gg.y + bb.y;
  o.z = d2 * inv * gg.z + bb.z;
  o.w = d3 * inv * gg.w + bb.w;
  if (out) ((float4*)(out + (size_t)row * DDIM))[lane] = o;
  if (outb) {
    ushort4 ob;
    ob.x = f2bf(o.x); ob.y = f2bf(o.y); ob.z = f2bf(o.z); ob.w = f2bf(o.w);
    *(ushort4*)(outb + (size_t)row * DDIM + lane * 4) = ob;
  }
}

// ---- host launch ----
extern "C" void kernel_launch(void* const* d_in, const int* in_sizes, int n_in,
                              void* d_out, int out_size, void* d_ws, size_t ws_size,
                              hipStream_t stream) {
  const float* x      = (const float*)d_in[0];
  const int*   ei     = (const int*)d_in[1];
  const int*   scm    = (const int*)d_in[2];
  const float* fcw    = (const float*)d_in[3];
  const float* in_w   = (const float*)d_in[4];
  const float* in_b   = (const float*)d_in[5];
  const float* st_emb = (const float*)d_in[6];
  const float* Wq     = (const float*)d_in[7];
  const float* Wk     = (const float*)d_in[8];
  const float* Wv     = (const float*)d_in[9];
  const float* Wo     = (const float*)d_in[10];
  const float* bo     = (const float*)d_in[11];
  const float* ln1g   = (const float*)d_in[12];
  const float* ln1b   = (const float*)d_in[13];
  const float* ln2g   = (const float*)d_in[14];
  const float* ln2b   = (const float*)d_in[15];
  const float* fw1    = (const float*)d_in[16];
  const float* fb1    = (const float*)d_in[17];
  const float* fw2    = (const float*)d_in[18];
  const float* fb2    = (const float*)d_in[19];
  const float* lam    = (const float*)d_in[20];
  const float* fus_w  = (const float*)d_in[21];
  const float* fus_b  = (const float*)d_in[22];
  const float* outg   = (const float*)d_in[23];
  const float* outb   = (const float*)d_in[24];

  const size_t ND = (size_t)N_NODES * DDIM;      // 5.12M
  const int DD = DDIM * DDIM;                     // 65536
  float* W = (float*)d_ws;
  size_t off = 0;
  auto alloc = [&](size_t n) { float* p = W + off; off += n; return p; };
  // union: f1 bf16 [N,1024] (40.96MB) | QKV bf16 [N,768] (30.72MB)
  float* u1 = alloc((size_t)N_NODES * 1024 / 2);
  unsigned short* f1  = (unsigned short*)u1;
  unsigned short* QKV = (unsigned short*)u1;
  unsigned short* aggb = (unsigned short*)alloc(ND / 2);
  float* h    = alloc(ND);
  float* out1 = alloc(ND);
  float* f2   = alloc(ND);
  unsigned short* h_bf   = (unsigned short*)alloc(ND / 2);
  unsigned short* out1_bf = (unsigned short*)alloc(ND / 2);
  unsigned short* bfb = (unsigned short*)alloc(1310720);  // 2,621,440 shorts
  unsigned short* wqkvT = bfb;                   // 3 * 768*256 = 589824
  unsigned short* woT   = bfb + 589824;          // 3 * 65536  = 196608
  unsigned short* fw1T  = bfb + 786432;          // 3 * 262144 = 786432
  unsigned short* fw2T  = bfb + 1572864;         // 3 * 262144
  unsigned short* fusT  = bfb + 2359296;         // 262144
  int*   rowptr = (int*)alloc(N_NODES + 4);
  int*   deg    = (int*)alloc(N_NODES);          // deg+cur contiguous
  int*   cur    = (int*)alloc(N_NODES);
  int*   epack  = (int*)alloc(EE);
  float* efw    = alloc(EE);
  float* bias2  = alloc(DDIM);
  float* fus    = (float*)d_out;

  // ---- weights -> bf16 transposed (once per launch) ----
  for (int l = 0; l < LL; l++) {
    unsigned short* qkvl = wqkvT + (size_t)l * 768 * 256;
    transpose_bf16_kernel<<<(DD + 255) / 256, 256, 0, stream>>>(Wq + (size_t)l * DD, qkvl,            DDIM, DDIM);
    transpose_bf16_kernel<<<(DD + 255) / 256, 256, 0, stream>>>(Wk + (size_t)l * DD, qkvl + 256*256,  DDIM, DDIM);
    transpose_bf16_kernel<<<(DD + 255) / 256, 256, 0, stream>>>(Wv + (size_t)l * DD, qkvl + 512*256,  DDIM, DDIM);
    transpose_bf16_kernel<<<(DD + 255) / 256, 256, 0, stream>>>(Wo + (size_t)l * DD, woT + (size_t)l * DD, DDIM, DDIM);
    transpose_bf16_kernel<<<(4 * DD + 255) / 256, 256, 0, stream>>>(fw1 + (size_t)l * 4 * DD, fw1T + (size_t)l * 4 * DD, DDIM, 4 * DDIM);
    transpose_bf16_kernel<<<(4 * DD + 255) / 256, 256, 0, stream>>>(fw2 + (size_t)l * 4 * DD, fw2T + (size_t)l * 4 * DD, 4 * DDIM, DDIM);
  }
  transpose_bf16_kernel<<<(4 * DD + 255) / 256, 256, 0, stream>>>(fus_w, fusT, 4 * DDIM, DDIM);

  const int gMn = (N_NODES + 127) / 128;         // 157
  dim3 gQKV(6, gMn), gFFN1(8, gMn), gD(2, gMn);
  dim3 gF32(DDIM / 64, (N_NODES + 63) / 64);
  const int lnBlocks = (N_NODES + 3) / 4;
  const int eBlocks = (EE + 255) / 256;
  const int n2Blocks = (2 * N_NODES + 255) / 256;

  for (int s = 0; s < SS; s++) {
    const int* srcp = ei + (size_t)s * 2 * EE;
    const int* dstp = srcp + EE;
    const int* scs  = scm + (size_t)s * EE;
    const float* fcs = fcw + (size_t)s * EE;

    // CSR build
    ifill_kernel<<<n2Blocks, 256, 0, stream>>>(deg, 0, 2 * N_NODES);  // deg+cur
    hist_kernel<<<eBlocks, 256, 0, stream>>>(dstp, deg);
    scan_kernel<<<1, 1024, 0, stream>>>(deg, rowptr);
    csrfill_kernel<<<eBlocks, 256, 0, stream>>>(srcp, dstp, scs, fcs, rowptr, cur, epack, efw);

    // h = x @ in_w + (in_b + stage_emb[s])   (dual f32 + bf16)
    bias2_kernel<<<1, DDIM, 0, stream>>>(in_b, st_emb + s * DDIM, bias2);
    gemm_f32_kernel<<<gF32, 256, 0, stream>>>(x, in_w, bias2, h, h_bf, N_NODES, DDIM, FDIM);

    for (int l = 0; l < LL; l++) {
      // fused QKV: [N,768] bf16
      mfma_gemm_bf<0, 1, false><<<gQKV, 256, 0, stream>>>(
          h_bf, wqkvT + (size_t)l * 768 * 256, nullptr, nullptr, QKV, 768,
          N_NODES, DDIM, DDIM, 0);

      attn_agg_kernel<<<lnBlocks, 256, 0, stream>>>(QKV, rowptr, epack, efw, lam, l, aggb);

      mfma_gemm_bf<0, 0, false><<<gD, 256, 0, stream>>>(
          aggb, woT + (size_t)l * DD, bo + l * DDIM, f2, nullptr, DDIM,
          N_NODES, DDIM, DDIM, 0);
      ln_kernel<<<lnBlocks, 256, 0, stream>>>(f2, h, ln1g + l * DDIM, ln1b + l * DDIM, out1, out1_bf, N_NODES);
      mfma_gemm_bf<1, 1, false><<<gFFN1, 256, 0, stream>>>(
          out1_bf, fw1T + (size_t)l * 4 * DD, fb1 + l * 4 * DDIM, nullptr, f1, 4 * DDIM,
          N_NODES, DDIM, DDIM, 0);
      mfma_gemm_bf<0, 0, false><<<gD, 256, 0, stream>>>(
          f1, fw2T + (size_t)l * 4 * DD, fb2 + l * DDIM, f2, nullptr, DDIM,
          N_NODES, 4 * DDIM, 4 * DDIM, 0);
      ln_kernel<<<lnBlocks, 256, 0, stream>>>(f2, out1, ln2g + l * DDIM, ln2b + l * DDIM, h, h_bf, N_NODES);
    }

    // fusion accumulate into d_out: fus (+)= h @ fus_w[s*D:(s+1)*D, :]
    if (s == 0)
      mfma_gemm_bf<0, 0, false><<<gD, 256, 0, stream>>>(
          h_bf, fusT, fus_b, fus, nullptr, DDIM, N_NODES, DDIM, 4 * DDIM, s * DDIM);
    else
      mfma_gemm_bf<0, 0, true><<<gD, 256, 0, stream>>>(
          h_bf, fusT, nullptr, fus, nullptr, DDIM, N_NODES, DDIM, 4 * DDIM, s * DDIM);
  }

  // final LN in-place on d_out
  ln_kernel<<<lnBlocks, 256, 0, stream>>>(fus, nullptr, outg, outb, (float*)d_out, nullptr, N_NODES);
}

// Round 5
// 2684.466 us; speedup vs baseline: 8.5778x; 1.1784x over previous
//
#include <hip/hip_runtime.h>
#include <hip/hip_bf16.h>
#include <math.h>

#define N_NODES 20000
#define FDIM 20
#define DDIM 256
#define HH 8
#define LL 3
#define SS 4
#define EE 320000

typedef __attribute__((ext_vector_type(8))) short bf16x8;
typedef __attribute__((ext_vector_type(8))) unsigned short u16x8;
typedef __attribute__((ext_vector_type(4))) float f32x4;

__device__ inline unsigned short f2bf(float f) {
  unsigned u = __float_as_uint(f);
  unsigned r = u + 0x7FFFu + ((u >> 16) & 1u);
  return (unsigned short)(r >> 16);
}
__device__ inline float bf2f(unsigned short u) {
  return __uint_as_float(((unsigned)u) << 16);
}

// ---- f32 GEMM (x@in_w, K=20): C = A@B + bias (f32 out) ----
__global__ __launch_bounds__(256) void gemm_f32_kernel(
    const float* __restrict__ A, const float* __restrict__ B,
    const float* __restrict__ bias, float* __restrict__ C,
    int M, int Nc, int K)
{
  __shared__ float As[16][65];
  __shared__ float Bs[16][65];
  const int tid = threadIdx.x;
  const int tx = tid & 15, ty = tid >> 4;
  const int row0 = blockIdx.y * 64, col0 = blockIdx.x * 64;
  const int am = tid >> 2, ak = (tid & 3) * 4;
  const int bk = tid >> 4, bc = (tid & 15) * 4;
  float acc[4][4] = {};
  for (int k0 = 0; k0 < K; k0 += 16) {
    float4 av = make_float4(0.f, 0.f, 0.f, 0.f);
    int garow = row0 + am;
    if (garow < M) {
      if (k0 + ak + 3 < K) {
        av = *(const float4*)(A + (size_t)garow * K + k0 + ak);
      } else {
        float t[4];
        #pragma unroll
        for (int j = 0; j < 4; j++)
          t[j] = (k0 + ak + j < K) ? A[(size_t)garow * K + k0 + ak + j] : 0.f;
        av = make_float4(t[0], t[1], t[2], t[3]);
      }
    }
    As[ak + 0][am] = av.x; As[ak + 1][am] = av.y;
    As[ak + 2][am] = av.z; As[ak + 3][am] = av.w;
    float4 bv = make_float4(0.f, 0.f, 0.f, 0.f);
    if (k0 + bk < K)
      bv = *(const float4*)(B + (size_t)(k0 + bk) * Nc + col0 + bc);
    Bs[bk][bc + 0] = bv.x; Bs[bk][bc + 1] = bv.y;
    Bs[bk][bc + 2] = bv.z; Bs[bk][bc + 3] = bv.w;
    __syncthreads();
    #pragma unroll
    for (int kk = 0; kk < 16; kk++) {
      float a[4], b[4];
      #pragma unroll
      for (int i = 0; i < 4; i++) a[i] = As[kk][ty * 4 + i];
      #pragma unroll
      for (int j = 0; j < 4; j++) b[j] = Bs[kk][tx * 4 + j];
      #pragma unroll
      for (int i = 0; i < 4; i++)
        #pragma unroll
        for (int j = 0; j < 4; j++)
          acc[i][j] = fmaf(a[i], b[j], acc[i][j]);
    }
    __syncthreads();
  }
  #pragma unroll
  for (int i = 0; i < 4; i++) {
    int row = row0 + ty * 4 + i;
    if (row >= M) continue;
    int col = col0 + tx * 4;
    float4 v;
    float* vp = &v.x;
    #pragma unroll
    for (int j = 0; j < 4; j++) vp[j] = acc[i][j] + bias[col + j];
    *(float4*)(C + (size_t)row * Nc + col) = v;
  }
}

// ---- generic bf16 MFMA GEMM, 64x128 tile, 4 waves (2x2), bf16 out ----
template<int ACT>
__global__ __launch_bounds__(256) void mfma_gemm64(
    const unsigned short* __restrict__ A, const unsigned short* __restrict__ BT,
    const float* __restrict__ bias, unsigned short* __restrict__ Cb,
    int ldc, int M, int K, int ldb)
{
  __shared__ unsigned short As[64][40];
  __shared__ unsigned short Bs[128][40];
  const int tid = threadIdx.x, lane = tid & 63, wid = tid >> 6;
  const int wr = (wid >> 1) * 32, wc = (wid & 1) * 64;
  const int row0 = blockIdx.y * 64, col0 = blockIdx.x * 128;
  const int sr = tid >> 2, sc = (tid & 3) * 8;
  f32x4 acc[2][4] = {};
  for (int k0 = 0; k0 < K; k0 += 32) {
    {
      int gr = row0 + sr;
      u16x8 av = {0,0,0,0,0,0,0,0};
      if (gr < M) av = *(const u16x8*)(A + (size_t)gr * K + k0 + sc);
      *(u16x8*)&As[sr][sc] = av;
    }
    #pragma unroll
    for (int p = 0; p < 2; p++) {
      int n = p * 64 + sr;
      u16x8 bv = *(const u16x8*)(BT + (size_t)(col0 + n) * ldb + k0 + sc);
      *(u16x8*)&Bs[n][sc] = bv;
    }
    __syncthreads();
    bf16x8 af[2], bfv[4];
    #pragma unroll
    for (int mi = 0; mi < 2; mi++)
      af[mi] = *(const bf16x8*)&As[wr + mi * 16 + (lane & 15)][(lane >> 4) * 8];
    #pragma unroll
    for (int ni = 0; ni < 4; ni++)
      bfv[ni] = *(const bf16x8*)&Bs[wc + ni * 16 + (lane & 15)][(lane >> 4) * 8];
    #pragma unroll
    for (int mi = 0; mi < 2; mi++)
      #pragma unroll
      for (int ni = 0; ni < 4; ni++)
        acc[mi][ni] = __builtin_amdgcn_mfma_f32_16x16x32_bf16(af[mi], bfv[ni], acc[mi][ni], 0, 0, 0);
    __syncthreads();
  }
  #pragma unroll
  for (int mi = 0; mi < 2; mi++) {
    #pragma unroll
    for (int ni = 0; ni < 4; ni++) {
      int col = col0 + wc + ni * 16 + (lane & 15);
      float bval = bias ? bias[col] : 0.f;
      #pragma unroll
      for (int j = 0; j < 4; j++) {
        int row = row0 + wr + mi * 16 + (lane >> 4) * 4 + j;
        if (row < M) {
          float t = acc[mi][ni][j] + bval;
          if (ACT == 1) t = 0.5f * t * (1.f + erff(t * 0.7071067811865475f));
          Cb[(size_t)row * ldc + col] = f2bf(t);
        }
      }
    }
  }
}

// ---- fused GEMM (+bias +resid) [+LN] kernel: 32 rows x 256 cols, 625 blocks ----
// DO_LN: out = LN(gemm+bias+resid)*g+b -> outf f32 + outb bf16
// !DO_LN: outf = gemm + bias [+ outf(ACCUM)]
template<int KTILES, int DO_LN, int ACCUM>
__global__ __launch_bounds__(256) void gemm_ln_kernel(
    const unsigned short* __restrict__ A, const unsigned short* __restrict__ BT,
    const float* __restrict__ bias, const float* __restrict__ resid,
    const float* __restrict__ gv, const float* __restrict__ bv,
    float* __restrict__ outf, unsigned short* __restrict__ outb,
    int M, int ldb, int bk0)
{
  constexpr int K = KTILES * 32;
  __shared__ unsigned short As[32][40];
  __shared__ unsigned short Bs[256][40];
  __shared__ float red[32][4][2];
  __shared__ float stats[32][2];
  const int tid = threadIdx.x, lane = tid & 63, w = tid >> 6;
  const int row0 = blockIdx.x * 32;
  const int sr2 = tid >> 3, sc2 = (tid & 7) * 4;
  const int sr = tid >> 2, sc = (tid & 3) * 8;
  const int g16 = lane >> 4, c15 = lane & 15;
  f32x4 acc[2][4] = {};
  for (int kt = 0; kt < KTILES; kt++) {
    int k0 = kt * 32;
    {
      int gr = row0 + sr2;
      ushort4 av = make_ushort4(0, 0, 0, 0);
      if (gr < M) av = *(const ushort4*)(A + (size_t)gr * K + k0 + sc2);
      *(ushort4*)&As[sr2][sc2] = av;
    }
    #pragma unroll
    for (int p = 0; p < 4; p++) {
      int n = p * 64 + sr;
      u16x8 bv8 = *(const u16x8*)(BT + (size_t)n * ldb + bk0 + k0 + sc);
      *(u16x8*)&Bs[n][sc] = bv8;
    }
    __syncthreads();
    bf16x8 af[2], bfv[4];
    #pragma unroll
    for (int mi = 0; mi < 2; mi++)
      af[mi] = *(const bf16x8*)&As[mi * 16 + c15][g16 * 8];
    #pragma unroll
    for (int ni = 0; ni < 4; ni++)
      bfv[ni] = *(const bf16x8*)&Bs[w * 64 + ni * 16 + c15][g16 * 8];
    #pragma unroll
    for (int mi = 0; mi < 2; mi++)
      #pragma unroll
      for (int ni = 0; ni < 4; ni++)
        acc[mi][ni] = __builtin_amdgcn_mfma_f32_16x16x32_bf16(af[mi], bfv[ni], acc[mi][ni], 0, 0, 0);
    __syncthreads();
  }
  // add bias / residual / accumulator, keep in acc
  #pragma unroll
  for (int mi = 0; mi < 2; mi++)
    #pragma unroll
    for (int ni = 0; ni < 4; ni++) {
      int col = w * 64 + ni * 16 + c15;
      float bval = bias ? bias[col] : 0.f;
      #pragma unroll
      for (int j = 0; j < 4; j++) {
        int row = row0 + mi * 16 + g16 * 4 + j;
        float t = acc[mi][ni][j] + bval;
        if (row < M) {
          if (DO_LN) t += resid[(size_t)row * DDIM + col];
          if (ACCUM) t += outf[(size_t)row * DDIM + col];
        }
        acc[mi][ni][j] = t;
      }
    }
  if (DO_LN) {
    #pragma unroll
    for (int mi = 0; mi < 2; mi++)
      #pragma unroll
      for (int j = 0; j < 4; j++) {
        float s = 0.f, q = 0.f;
        #pragma unroll
        for (int ni = 0; ni < 4; ni++) { float t = acc[mi][ni][j]; s += t; q += t * t; }
        #pragma unroll
        for (int d = 1; d < 16; d <<= 1) { s += __shfl_xor(s, d); q += __shfl_xor(q, d); }
        if (c15 == 0) {
          int r = mi * 16 + g16 * 4 + j;
          red[r][w][0] = s; red[r][w][1] = q;
        }
      }
    __syncthreads();
    if (tid < 32) {
      float s = red[tid][0][0] + red[tid][1][0] + red[tid][2][0] + red[tid][3][0];
      float q = red[tid][0][1] + red[tid][1][1] + red[tid][2][1] + red[tid][3][1];
      float mu = s * (1.f / DDIM);
      float var = q * (1.f / DDIM) - mu * mu;
      stats[tid][0] = mu;
      stats[tid][1] = rsqrtf(var + 1e-5f);
    }
    __syncthreads();
  }
  #pragma unroll
  for (int mi = 0; mi < 2; mi++)
    #pragma unroll
    for (int ni = 0; ni < 4; ni++) {
      int col = w * 64 + ni * 16 + c15;
      #pragma unroll
      for (int j = 0; j < 4; j++) {
        int r = mi * 16 + g16 * 4 + j;
        int row = row0 + r;
        if (row >= M) continue;
        float t = acc[mi][ni][j];
        float o = DO_LN ? (t - stats[r][0]) * stats[r][1] * gv[col] + bv[col] : t;
        outf[(size_t)row * DDIM + col] = o;
        if (DO_LN) outb[(size_t)row * DDIM + col] = f2bf(o);
      }
    }
}

// ---- tiled coalesced transpose f32 -> bf16: WT[n*ldo+k] = bf16(W[k*Nn+n]) ----
__global__ __launch_bounds__(256) void transpose_bf16_tiled(
    const float* __restrict__ W, unsigned short* __restrict__ WT,
    int K, int Nn, int ldo, size_t istr, size_t ostr)
{
  __shared__ unsigned short t[64][65];
  const float* src = W + blockIdx.z * istr;
  unsigned short* dst = WT + blockIdx.z * ostr;
  int tid = threadIdx.x;
  int ty = tid >> 4, tx = tid & 15;
  int k0 = blockIdx.y * 64, n0 = blockIdx.x * 64;
  #pragma unroll
  for (int r = 0; r < 4; r++) {
    int k = k0 + r * 16 + ty;
    float4 v = *(const float4*)(src + (size_t)k * Nn + n0 + tx * 4);
    t[tx * 4 + 0][r * 16 + ty] = f2bf(v.x);
    t[tx * 4 + 1][r * 16 + ty] = f2bf(v.y);
    t[tx * 4 + 2][r * 16 + ty] = f2bf(v.z);
    t[tx * 4 + 3][r * 16 + ty] = f2bf(v.w);
  }
  __syncthreads();
  #pragma unroll
  for (int r = 0; r < 4; r++) {
    int n = r * 16 + ty;
    ushort4 o;
    o.x = t[n][tx * 4 + 0]; o.y = t[n][tx * 4 + 1];
    o.z = t[n][tx * 4 + 2]; o.w = t[n][tx * 4 + 3];
    *(ushort4*)(dst + (size_t)(n0 + n) * ldo + k0 + tx * 4) = o;
  }
}

// ---- helpers ----
__global__ void ifill_kernel(int* __restrict__ p, int v, int n) {
  int i = blockIdx.x * blockDim.x + threadIdx.x;
  if (i < n) p[i] = v;
}

__global__ void add_emb_dual(const float* __restrict__ base, const float* __restrict__ se,
                             float* __restrict__ h, unsigned short* __restrict__ hb) {
  int i4 = blockIdx.x * blockDim.x + threadIdx.x;
  if (i4 >= N_NODES * 64) return;
  float4 v = ((const float4*)base)[i4];
  float4 e = ((const float4*)se)[i4 & 63];
  v.x += e.x; v.y += e.y; v.z += e.z; v.w += e.w;
  ((float4*)h)[i4] = v;
  ushort4 o;
  o.x = f2bf(v.x); o.y = f2bf(v.y); o.z = f2bf(v.z); o.w = f2bf(v.w);
  ((ushort4*)hb)[i4] = o;
}

// ---- CSR build ----
__global__ void hist_kernel(const int* __restrict__ dst, int* __restrict__ deg) {
  int e = blockIdx.x * blockDim.x + threadIdx.x;
  if (e < EE) atomicAdd(&deg[dst[e]], 1);
}

__global__ __launch_bounds__(1024) void scan_kernel(const int* __restrict__ deg,
                                                    int* __restrict__ rowptr) {
  __shared__ int part[1024];
  const int t = threadIdx.x;
  const int CH = (N_NODES + 1023) / 1024;
  int base = t * CH, s = 0;
  for (int i = 0; i < CH; i++) {
    int idx = base + i;
    if (idx < N_NODES) s += deg[idx];
  }
  part[t] = s;
  __syncthreads();
  for (int off = 1; off < 1024; off <<= 1) {
    int v = (t >= off) ? part[t - off] : 0;
    __syncthreads();
    part[t] += v;
    __syncthreads();
  }
  int run = (t == 0) ? 0 : part[t - 1];
  for (int i = 0; i < CH; i++) {
    int idx = base + i;
    if (idx < N_NODES) { rowptr[idx] = run; run += deg[idx]; }
  }
  if (t == 1023) rowptr[N_NODES] = run;
}

__global__ void csrfill_kernel(const int* __restrict__ src, const int* __restrict__ dst,
                               const int* __restrict__ scm, const float* __restrict__ fcw,
                               const int* __restrict__ rowptr, int* __restrict__ cur,
                               int2* __restrict__ epe) {
  int e = blockIdx.x * blockDim.x + threadIdx.x;
  if (e >= EE) return;
  int d = dst[e];
  int slot = rowptr[d] + atomicAdd(&cur[d], 1);
  epe[slot] = make_int2(src[e] | (scm[e] << 31), __float_as_int(fcw[e]));
}

// ---- fused edge attention + aggregation, 2-edge software pipeline ----
// QKV row layout per node: [Q 256 | K 256 | V 256] bf16, stride 768.
__global__ __launch_bounds__(256) void attn_agg_kernel(
    const unsigned short* __restrict__ QKV,
    const int* __restrict__ rowptr, const int2* __restrict__ epe,
    const float* __restrict__ lam, int l,
    unsigned short* __restrict__ agg)
{
  int node = blockIdx.x * 4 + (threadIdx.x >> 6);
  int lane = threadIdx.x & 63;
  if (node >= N_NODES) return;
  const float laml = lam[l];
  ushort4 q4 = *(const ushort4*)(QKV + (size_t)node * 768 + lane * 4);
  float qx = bf2f(q4.x), qy = bf2f(q4.y), qz = bf2f(q4.z), qw = bf2f(q4.w);
  int beg = rowptr[node], end = rowptr[node + 1];
  float m = -INFINITY, ss = 0.f;
  float ax = 0.f, ay = 0.f, az = 0.f, aw = 0.f;
  int i = beg;
  for (; i + 1 < end; i += 2) {
    int2 ea = epe[i], eb = epe[i + 1];
    int sa = ea.x & 0x7FFFFFFF, sb = eb.x & 0x7FFFFFFF;
    float sca = (float)(((unsigned)ea.x) >> 31);
    float scb = (float)(((unsigned)eb.x) >> 31);
    float fwa = __int_as_float(ea.y), fwb = __int_as_float(eb.y);
    const unsigned short* kpa = QKV + (size_t)sa * 768 + 256 + lane * 4;
    const unsigned short* kpb = QKV + (size_t)sb * 768 + 256 + lane * 4;
    ushort4 ka = *(const ushort4*)kpa;
    ushort4 va = *(const ushort4*)(kpa + 256);
    ushort4 kb = *(const ushort4*)kpb;
    ushort4 vb = *(const ushort4*)(kpb + 256);
    float da = qx * bf2f(ka.x) + qy * bf2f(ka.y) + qz * bf2f(ka.z) + qw * bf2f(ka.w);
    float db = qx * bf2f(kb.x) + qy * bf2f(kb.y) + qz * bf2f(kb.z) + qw * bf2f(kb.w);
    da += __shfl_xor(da, 1); db += __shfl_xor(db, 1);
    da += __shfl_xor(da, 2); db += __shfl_xor(db, 2);
    da += __shfl_xor(da, 4); db += __shfl_xor(db, 4);
    float s0 = da * 0.17677669529663687f * sca + laml * fwa;
    float s1 = db * 0.17677669529663687f * scb + laml * fwb;
    float mn = fmaxf(m, fmaxf(s0, s1));
    float corr = __expf(m - mn);
    float p0 = __expf(s0 - mn);
    float p1 = __expf(s1 - mn);
    ss = ss * corr + p0 + p1;
    ax = ax * corr + p0 * bf2f(va.x) + p1 * bf2f(vb.x);
    ay = ay * corr + p0 * bf2f(va.y) + p1 * bf2f(vb.y);
    az = az * corr + p0 * bf2f(va.z) + p1 * bf2f(vb.z);
    aw = aw * corr + p0 * bf2f(va.w) + p1 * bf2f(vb.w);
    m = mn;
  }
  if (i < end) {
    int2 ea = epe[i];
    int sa = ea.x & 0x7FFFFFFF;
    float sca = (float)(((unsigned)ea.x) >> 31);
    float fwa = __int_as_float(ea.y);
    const unsigned short* kpa = QKV + (size_t)sa * 768 + 256 + lane * 4;
    ushort4 ka = *(const ushort4*)kpa;
    ushort4 va = *(const ushort4*)(kpa + 256);
    float da = qx * bf2f(ka.x) + qy * bf2f(ka.y) + qz * bf2f(ka.z) + qw * bf2f(ka.w);
    da += __shfl_xor(da, 1);
    da += __shfl_xor(da, 2);
    da += __shfl_xor(da, 4);
    float s0 = da * 0.17677669529663687f * sca + laml * fwa;
    float mn = fmaxf(m, s0);
    float corr = __expf(m - mn);
    float p0 = __expf(s0 - mn);
    ss = ss * corr + p0;
    ax = ax * corr + p0 * bf2f(va.x);
    ay = ay * corr + p0 * bf2f(va.y);
    az = az * corr + p0 * bf2f(va.z);
    aw = aw * corr + p0 * bf2f(va.w);
    m = mn;
  }
  float inv = 1.f / (ss + 1e-16f);
  ushort4 o;
  o.x = f2bf(ax * inv); o.y = f2bf(ay * inv);
  o.z = f2bf(az * inv); o.w = f2bf(aw * inv);
  *(ushort4*)(agg + (size_t)node * DDIM + lane * 4) = o;
}

// ---- standalone LayerNorm (final output only) ----
__global__ __launch_bounds__(256) void ln_kernel(
    const float* __restrict__ X, const float* __restrict__ g,
    const float* __restrict__ b, float* __restrict__ out, int M)
{
  int row = blockIdx.x * (blockDim.x >> 6) + (threadIdx.x >> 6);
  int lane = threadIdx.x & 63;
  if (row >= M) return;
  float4 x = ((const float4*)(X + (size_t)row * DDIM))[lane];
  float s = x.x + x.y + x.z + x.w;
  #pragma unroll
  for (int mk = 1; mk < 64; mk <<= 1) s += __shfl_xor(s, mk);
  float mu = s * (1.f / DDIM);
  float d0 = x.x - mu, d1 = x.y - mu, d2 = x.z - mu, d3 = x.w - mu;
  float vs = d0 * d0 + d1 * d1 + d2 * d2 + d3 * d3;
  #pragma unroll
  for (int mk = 1; mk < 64; mk <<= 1) vs += __shfl_xor(vs, mk);
  float inv = rsqrtf(vs * (1.f / DDIM) + 1e-5f);
  float4 gg = ((const float4*)g)[lane];
  float4 bb = ((const float4*)b)[lane];
  float4 o;
  o.x = d0 * inv * gg.x + bb.x;
  o.y = d1 * inv * gg.y + bb.y;
  o.z = d2 * inv * gg.z + bb.z;
  o.w = d3 * inv * gg.w + bb.w;
  ((float4*)(out + (size_t)row * DDIM))[lane] = o;
}

// ---- host launch ----
extern "C" void kernel_launch(void* const* d_in, const int* in_sizes, int n_in,
                              void* d_out, int out_size, void* d_ws, size_t ws_size,
                              hipStream_t stream) {
  const float* x      = (const float*)d_in[0];
  const int*   ei     = (const int*)d_in[1];
  const int*   scm    = (const int*)d_in[2];
  const float* fcw    = (const float*)d_in[3];
  const float* in_w   = (const float*)d_in[4];
  const float* in_b   = (const float*)d_in[5];
  const float* st_emb = (const float*)d_in[6];
  const float* Wq     = (const float*)d_in[7];
  const float* Wk     = (const float*)d_in[8];
  const float* Wv     = (const float*)d_in[9];
  const float* Wo     = (const float*)d_in[10];
  const float* bo     = (const float*)d_in[11];
  const float* ln1g   = (const float*)d_in[12];
  const float* ln1b   = (const float*)d_in[13];
  const float* ln2g   = (const float*)d_in[14];
  const float* ln2b   = (const float*)d_in[15];
  const float* fw1    = (const float*)d_in[16];
  const float* fb1    = (const float*)d_in[17];
  const float* fw2    = (const float*)d_in[18];
  const float* fb2    = (const float*)d_in[19];
  const float* lam    = (const float*)d_in[20];
  const float* fus_w  = (const float*)d_in[21];
  const float* fus_b  = (const float*)d_in[22];
  const float* outg   = (const float*)d_in[23];
  const float* outb   = (const float*)d_in[24];

  const size_t ND = (size_t)N_NODES * DDIM;   // 5.12M
  const int DD = DDIM * DDIM;                  // 65536
  float* W = (float*)d_ws;
  size_t off = 0;
  auto alloc = [&](size_t n) { float* p = W + off; off += n; return p; };
  // union: f1 bf16 [N,1024] | QKV bf16 [N,768]
  float* u1 = alloc((size_t)N_NODES * 1024 / 2);
  unsigned short* f1  = (unsigned short*)u1;
  unsigned short* QKV = (unsigned short*)u1;
  unsigned short* aggb    = (unsigned short*)alloc(ND / 2);
  float* base = alloc(ND);
  float* h    = alloc(ND);
  float* out1 = alloc(ND);
  unsigned short* h_bf    = (unsigned short*)alloc(ND / 2);
  unsigned short* out1_bf = (unsigned short*)alloc(ND / 2);
  unsigned short* bfb = (unsigned short*)alloc(1310720);  // 2,621,440 shorts
  unsigned short* wqkvT = bfb;                   // 3 * 196608
  unsigned short* woT   = bfb + 589824;          // 3 * 65536
  unsigned short* fw1T  = bfb + 786432;          // 3 * 262144
  unsigned short* fw2T  = bfb + 1572864;         // 3 * 262144
  unsigned short* fusT  = bfb + 2359296;         // 262144
  int*  rowptr = (int*)alloc(N_NODES + 4);
  int*  deg    = (int*)alloc(N_NODES);
  int*  cur    = (int*)alloc(N_NODES);
  int2* epe    = (int2*)alloc(EE * 2);
  float* fus   = (float*)d_out;

  // ---- weights -> bf16 transposed (batched over layers, coalesced tiled) ----
  transpose_bf16_tiled<<<dim3(4, 4, 3), 256, 0, stream>>>(Wq, wqkvT,           DDIM, DDIM, DDIM, DD, 196608);
  transpose_bf16_tiled<<<dim3(4, 4, 3), 256, 0, stream>>>(Wk, wqkvT + 65536,   DDIM, DDIM, DDIM, DD, 196608);
  transpose_bf16_tiled<<<dim3(4, 4, 3), 256, 0, stream>>>(Wv, wqkvT + 131072,  DDIM, DDIM, DDIM, DD, 196608);
  transpose_bf16_tiled<<<dim3(4, 4, 3), 256, 0, stream>>>(Wo, woT,             DDIM, DDIM, DDIM, DD, DD);
  transpose_bf16_tiled<<<dim3(16, 4, 3), 256, 0, stream>>>(fw1, fw1T, DDIM, 4 * DDIM, DDIM, 4 * DD, 4 * DD);
  transpose_bf16_tiled<<<dim3(4, 16, 3), 256, 0, stream>>>(fw2, fw2T, 4 * DDIM, DDIM, 4 * DDIM, 4 * DD, 4 * DD);
  transpose_bf16_tiled<<<dim3(4, 16, 1), 256, 0, stream>>>(fus_w, fusT, 4 * DDIM, DDIM, 4 * DDIM, 0, 0);

  // base = x @ in_w + in_b (once; stage emb added per stage)
  dim3 gF32(DDIM / 64, (N_NODES + 63) / 64);
  gemm_f32_kernel<<<gF32, 256, 0, stream>>>(x, in_w, in_b, base, N_NODES, DDIM, FDIM);

  const int eBlocks  = (EE + 255) / 256;
  const int n2Blocks = (2 * N_NODES + 255) / 256;
  const int lnBlocks = (N_NODES + 3) / 4;
  const int emBlocks = (N_NODES * 64 + 255) / 256;
  dim3 gQKV(6, (N_NODES + 63) / 64);   // 64x128 tiles
  dim3 gFFN1(8, (N_NODES + 63) / 64);
  const int fusedBlocks = (N_NODES + 31) / 32;   // 625

  for (int s = 0; s < SS; s++) {
    const int* srcp = ei + (size_t)s * 2 * EE;
    const int* dstp = srcp + EE;
    const int* scs  = scm + (size_t)s * EE;
    const float* fcs = fcw + (size_t)s * EE;

    // CSR build
    ifill_kernel<<<n2Blocks, 256, 0, stream>>>(deg, 0, 2 * N_NODES);
    hist_kernel<<<eBlocks, 256, 0, stream>>>(dstp, deg);
    scan_kernel<<<1, 1024, 0, stream>>>(deg, rowptr);
    csrfill_kernel<<<eBlocks, 256, 0, stream>>>(srcp, dstp, scs, fcs, rowptr, cur, epe);

    // h = base + stage_emb[s]  (f32 + bf16)
    add_emb_dual<<<emBlocks, 256, 0, stream>>>(base, st_emb + s * DDIM, h, h_bf);

    for (int l = 0; l < LL; l++) {
      // fused QKV: [N,768] bf16
      mfma_gemm64<0><<<gQKV, 256, 0, stream>>>(
          h_bf, wqkvT + (size_t)l * 196608, nullptr, QKV, 768, N_NODES, DDIM, DDIM);

      attn_agg_kernel<<<lnBlocks, 256, 0, stream>>>(QKV, rowptr, epe, lam, l, aggb);

      // Wo + bias + resid(h) + LN1 -> out1 (f32+bf16)
      gemm_ln_kernel<8, 1, 0><<<fusedBlocks, 256, 0, stream>>>(
          aggb, woT + (size_t)l * DD, bo + l * DDIM, h,
          ln1g + l * DDIM, ln1b + l * DDIM, out1, out1_bf, N_NODES, DDIM, 0);

      // FFN1 + gelu -> f1 bf16
      mfma_gemm64<1><<<gFFN1, 256, 0, stream>>>(
          out1_bf, fw1T + (size_t)l * 4 * DD, fb1 + l * 4 * DDIM, f1, 4 * DDIM,
          N_NODES, DDIM, DDIM);

      // FFN2 + bias + resid(out1) + LN2 -> h (f32+bf16)
      gemm_ln_kernel<32, 1, 0><<<fusedBlocks, 256, 0, stream>>>(
          f1, fw2T + (size_t)l * 4 * DD, fb2 + l * DDIM, out1,
          ln2g + l * DDIM, ln2b + l * DDIM, h, h_bf, N_NODES, 4 * DDIM, 0);
    }

    // fusion accumulate into d_out
    if (s == 0)
      gemm_ln_kernel<8, 0, 0><<<fusedBlocks, 256, 0, stream>>>(
          h_bf, fusT, fus_b, nullptr, nullptr, nullptr, fus, nullptr,
          N_NODES, 4 * DDIM, s * DDIM);
    else
      gemm_ln_kernel<8, 0, 1><<<fusedBlocks, 256, 0, stream>>>(
          h_bf, fusT, nullptr, nullptr, nullptr, nullptr, fus, nullptr,
          N_NODES, 4 * DDIM, s * DDIM);
  }

  // final LN in-place on d_out
  ln_kernel<<<lnBlocks, 256, 0, stream>>>(fus, outg, outb, (float*)d_out, N_NODES);
}